// Round 3
// baseline (56.725 us; speedup 1.0000x reference)
//
#include <hip/hip_runtime.h>
#include <hip/hip_bf16.h>

// RandomShiftsAug on 1x1 spatial maps: out[i,:] = x[i,:] if (h1[i]==pad && w1[i]==pad) else 0.
// N = 16384 rows, C = 4096 floats/row.
//
// Memory-bound: 256 MB write is mandatory; x read is only needed for ~1/81 of
// rows (keep probability), so we branch per row and never read x for dropped
// rows. One block per row, 16B/lane vector stores, nontemporal (nt) to avoid
// L2 write-allocate pollution on the 268 MB streaming output.
//
// Note: __builtin_nontemporal_* requires a native vector type, not HIP's
// float4 struct wrapper — use clang ext_vector_type(4).

#define C_DIM 4096
#define C4 (C_DIM / 4)   // 1024 vec4 per row

typedef float f32x4 __attribute__((ext_vector_type(4)));

__global__ void __launch_bounds__(256)
random_shifts_kernel(const float* __restrict__ x,
                     const int* __restrict__ h1,
                     const int* __restrict__ w1,
                     const int* __restrict__ pad,
                     float* __restrict__ out,
                     int n_rows) {
    const int row = blockIdx.x;
    if (row >= n_rows) return;

    const int p = pad[0];
    // Wave-uniform per row: no divergence within the block.
    const bool keep = (h1[row] == p) && (w1[row] == p);

    const size_t base = (size_t)row * C_DIM;
    f32x4* __restrict__ orow = reinterpret_cast<f32x4*>(out + base);

    if (keep) {
        const f32x4* __restrict__ xrow = reinterpret_cast<const f32x4*>(x + base);
        #pragma unroll
        for (int i = threadIdx.x; i < C4; i += 256) {
            f32x4 v = __builtin_nontemporal_load(&xrow[i]);
            __builtin_nontemporal_store(v, &orow[i]);
        }
    } else {
        const f32x4 z = (f32x4)(0.f);
        #pragma unroll
        for (int i = threadIdx.x; i < C4; i += 256) {
            __builtin_nontemporal_store(z, &orow[i]);
        }
    }
}

extern "C" void kernel_launch(void* const* d_in, const int* in_sizes, int n_in,
                              void* d_out, int out_size, void* d_ws, size_t ws_size,
                              hipStream_t stream) {
    const float* x  = (const float*)d_in[0];
    const int*   h1 = (const int*)d_in[1];
    const int*   w1 = (const int*)d_in[2];
    const int*   pad = (const int*)d_in[3];
    float* out = (float*)d_out;

    const int n_rows = in_sizes[1];  // 16384

    random_shifts_kernel<<<n_rows, 256, 0, stream>>>(x, h1, w1, pad, out, n_rows);
}

// Round 4
// 42.149 us; speedup vs baseline: 1.3458x; 1.3458x over previous
//
#include <hip/hip_runtime.h>
#include <hip/hip_bf16.h>

// RandomShiftsAug on 1x1 spatial maps: out[i,:] = x[i,:] if (h1[i]==pad && w1[i]==pad) else 0.
// N = 16384 rows, C = 4096 floats/row.
//
// Memory-bound: 268 MB write is mandatory; x read only for ~1/81 of rows.
// Round-3 lesson: nontemporal stores HURT on gfx950 (42.3 -> 56.7 us) — plain
// stores use the fast L2 write path (the rocclr fill kernel gets 87% of peak
// with plain stores). This round: 8 rows/block so the per-block index loads
// (block-uniform -> scalar s_load, issued together) amortize over 32 stores
// per thread instead of 4, hiding block-start latency + dispatch ramp.

#define C_DIM 4096
#define C4 (C_DIM / 4)     // 1024 vec4 per row
#define RPB 8              // rows per block

typedef float f32x4 __attribute__((ext_vector_type(4)));

__global__ void __launch_bounds__(256)
random_shifts_kernel(const float* __restrict__ x,
                     const int* __restrict__ h1,
                     const int* __restrict__ w1,
                     const int* __restrict__ pad,
                     float* __restrict__ out) {
    const int row0 = blockIdx.x * RPB;
    const int p = pad[0];

    // Block-uniform index loads -> scalar loads, all in flight before one wait.
    bool keep[RPB];
    #pragma unroll
    for (int r = 0; r < RPB; ++r) {
        keep[r] = (h1[row0 + r] == p) && (w1[row0 + r] == p);
    }

    #pragma unroll
    for (int r = 0; r < RPB; ++r) {
        const size_t base = (size_t)(row0 + r) * C_DIM;
        f32x4* __restrict__ orow = reinterpret_cast<f32x4*>(out + base);
        if (keep[r]) {
            const f32x4* __restrict__ xrow = reinterpret_cast<const f32x4*>(x + base);
            #pragma unroll
            for (int j = 0; j < 4; ++j) {
                const int i = threadIdx.x + j * 256;
                orow[i] = xrow[i];
            }
        } else {
            const f32x4 z = (f32x4)(0.f);
            #pragma unroll
            for (int j = 0; j < 4; ++j) {
                const int i = threadIdx.x + j * 256;
                orow[i] = z;
            }
        }
    }
}

extern "C" void kernel_launch(void* const* d_in, const int* in_sizes, int n_in,
                              void* d_out, int out_size, void* d_ws, size_t ws_size,
                              hipStream_t stream) {
    const float* x  = (const float*)d_in[0];
    const int*   h1 = (const int*)d_in[1];
    const int*   w1 = (const int*)d_in[2];
    const int*   pad = (const int*)d_in[3];
    float* out = (float*)d_out;

    const int n_rows = in_sizes[1];  // 16384
    const int n_blocks = n_rows / RPB;  // 2048

    random_shifts_kernel<<<n_blocks, 256, 0, stream>>>(x, h1, w1, pad, out);
}